// Round 19
// baseline (363.437 us; speedup 1.0000x reference)
//
#include <hip/hip_runtime.h>

// ---------------------------------------------------------------------------
// STFT-Fourier-KAN DGCNN on MI355X.
// R18 post-mortem: kan<2> 77us, MfmaUtil 25.5% (=19.6us floor), VALU 51%
// (=39us) -- approaching VALU-bound, and HALF the VALU is self-inflicted:
// y-grid of 2 col-halves recomputes every row's features twice.
// R19: single-pass kan<2>: NT=128, 320-thr blocks (5 waves x 32 rows = 160
// rows = 8 points), features computed once. LDS union: slab(21.8K)+dbuf
// B(16.6K) during K-loop; same 43.5K region becomes the block-wide C-stage
// for the fused maxpool (barrier-guarded) -> 3 blocks/CU (47% occ cap).
// Also: seg2 merged into l4 (reads pmax/psum directly, same reduce order).
// ---------------------------------------------------------------------------

typedef unsigned short u16;
typedef unsigned int   u32;
typedef unsigned long long u64;
typedef __attribute__((ext_vector_type(8))) _Float16 half8;
typedef __attribute__((ext_vector_type(4))) float f32x4;

__device__ __forceinline__ float bf2f(u16 u) {
  u32 v = ((u32)u) << 16;
  return __uint_as_float(v);
}
__device__ __forceinline__ u16 f2bfr(float f) {  // bf16 round-to-nearest-even
  u32 x = __float_as_uint(f);
  u32 r = x + 0x7FFFu + ((x >> 16) & 1u);
  return (u16)(r >> 16);
}
__device__ __forceinline__ u16 f2h(float f) {    // fp16 RTN bits
  _Float16 h = (_Float16)f;
  u16 r;
  __builtin_memcpy(&r, &h, 2);
  return r;
}
__device__ __forceinline__ float h2f(u16 u) {
  _Float16 h;
  __builtin_memcpy(&h, &u, 2);
  return (float)h;
}
// dtype-dispatched external load (flag wave-uniform -> scalar branch)
__device__ __forceinline__ float ldf(const void* p, size_t i, bool f32) {
  return f32 ? ((const float*)p)[i] : bf2f(((const u16*)p)[i]);
}
__device__ __forceinline__ u64 minu64(u64 a, u64 b) { return a < b ? a : b; }

// ---------------- workspace layout (bytes) ----------------
#define NBR_OFF   ((size_t)0)                       // int32 [163840]       655,360
#define FLAG_OFF  ((size_t)917504)                  // int32 [1]
#define L4P_OFF   (((size_t)(1u << 20)) + 131072)   // f32 [8][15][240]     115,200
#define C1T_OFF   (((size_t)(1u << 20)) + 524288)   // fp16 [64][64]          8,192
#define C2T_OFF   (((size_t)(1u << 20)) + 589824)   // fp16 [128][1120]     286,720
#define C3T_OFF   ((size_t)(2u << 20))              // fp16 [1024][2240]  4,587,520
#define C4T_OFF   ((size_t)(7u << 20))              // f32  [40][38400]   6,144,000
#define PMAX_OFF  ((size_t)(13u << 20))             // f32 [256][1024]    1,048,576
#define PSUM_OFF  ((size_t)(14u << 20))             // f32 [256][1024]    1,048,576
#define X1_OFF    ((size_t)(15u << 20))             // fp16 [8192][128]   2,097,152
#define H1_OFF    ((size_t)(18u << 20))             // fp16 [163840][64] 20,971,520
// peak ~39 MB

// ---------------- dtype detector -------------------------------------------
__global__ void detect_kernel(const void* __restrict__ pos,
                              int* __restrict__ flag) {
  int t = threadIdx.x;  // 64 threads
  float a = fabsf(((const float*)pos)[t]);
  bool ok = (a > 1.0e-3f && a < 100.0f);
  unsigned long long m = __ballot(ok);
  if (t == 0) *flag = (__popcll(m) >= 32) ? 1 : 0;  // 1 = fp32 externals
}

// ---------------- merged coeff transpose: all four tensors ------------------
// Angle-major global order: p < 4*NA: aa=p>>2, g=(p&3)+1 ;
// p in [4*NA,5*NA): aa=p-4*NA, g=5. f = 2*p + part. Pad f>=Kt with zeros.
// Block ranges: c1 [0,16) c2 [16,576) c3 [576,9536) c4 [9536,15536).
__global__ void tkan_all_kernel(const void* __restrict__ s1, void* __restrict__ d1,
                                const void* __restrict__ s2, void* __restrict__ d2,
                                const void* __restrict__ s3, void* __restrict__ d3,
                                const void* __restrict__ s4, void* __restrict__ d4,
                                const int* __restrict__ dfl) {
  const int blk = blockIdx.x;
  const void* src; void* dst;
  int dout, nw, W, total, KPAD, outf32, base;
  if (blk < 16)        { src = s1; dst = d1; dout = 64;   nw = 2;  W = 3;
                         total = 64 * 64;     KPAD = 64;    outf32 = 0; base = 0; }
  else if (blk < 576)  { src = s2; dst = d2; dout = 128;  nw = 7;  W = 16;
                         total = 128 * 1120;  KPAD = 1120;  outf32 = 0; base = 16; }
  else if (blk < 9536) { src = s3; dst = d3; dout = 1024; nw = 7;  W = 32;
                         total = 1024 * 2240; KPAD = 2240;  outf32 = 0; base = 576; }
  else                 { src = s4; dst = d4; dout = 40;   nw = 15; W = 256;
                         total = 40 * 38400;  KPAD = 38400; outf32 = 1; base = 9536; }
  int id = (blk - base) * 256 + threadIdx.x;
  if (id >= total) return;
  const bool f32 = (*dfl != 0);
  int o = id / KPAD, f = id % KPAD;
  int NA = nw * W;
  int Kt = NA * 10;
  float v = 0.f;
  if (f < Kt) {
    int part = f & 1, p = f >> 1;
    int aa, gg;
    if (p < 4 * NA) { aa = p >> 2;      gg = p & 3; }
    else            { aa = p - 4 * NA;  gg = 4;     }
    int i = aa % W, w = aa / W;
    int OS = NA * 5;
    size_t sidx = (size_t)part * (dout * OS) + (size_t)o * OS + w * (W * 5) + i * 5 + gg;
    v = ldf(src, sidx, f32);
  }
  if (outf32) ((float*)dst)[id] = v;
  else        ((u16*)dst)[id] = f2h(v);
}

// ---------------- brute-force kNN: one wave per query -----------------------
__global__ __launch_bounds__(256) void knn_kernel(const void* __restrict__ pos,
                                                  int* __restrict__ nbr,
                                                  const int* __restrict__ dfl) {
  __shared__ float px[1024], py[1024], pz[1024];
  const bool f32 = (*dfl != 0);
  const int t = threadIdx.x;
  const int b = blockIdx.y;
  const int base = b << 10;
  for (int j = t; j < 1024; j += 256) {
    size_t pidx = (size_t)(base + j) * 3;
    px[j] = ldf(pos, pidx, f32);
    py[j] = ldf(pos, pidx + 1, f32);
    pz[j] = ldf(pos, pidx + 2, f32);
  }
  __syncthreads();
  const int wv = t >> 6, lane = t & 63;
  const int q = blockIdx.x * 4 + wv;
  const float qx = px[q], qy = py[q], qz = pz[q];
  u64 key[16];
#pragma unroll
  for (int s = 0; s < 16; ++s) {
    const int j = s * 64 + lane;
    float dx = qx - px[j], dy = qy - py[j], dz = qz - pz[j];
    float d = __fadd_rn(__fadd_rn(__fmul_rn(dx, dx), __fmul_rn(dy, dy)),
                        __fmul_rn(dz, dz));
    key[s] = (j == q) ? ~0ull
                      : ((((u64)__float_as_uint(d)) << 32) | (u32)j);
  }
  const int obase = (base + q) * 20;
  for (int k = 0; k < 20; ++k) {
    u64 m = key[0];
#pragma unroll
    for (int s = 1; s < 16; ++s) m = minu64(m, key[s]);
#pragma unroll
    for (int off = 32; off >= 1; off >>= 1) {
      u32 lo = (u32)m, hi = (u32)(m >> 32);
      lo = __shfl_xor(lo, off, 64);
      hi = __shfl_xor(hi, off, 64);
      m = minu64(m, (((u64)hi) << 32) | lo);
    }
    if (lane == 0) nbr[obase + k] = (int)(u32)m;
#pragma unroll
    for (int s = 0; s < 16; ++s)
      if (key[s] == m) key[s] = ~0ull;  // idx embedded -> unique, safe
  }
}

// ---------------- MFMA KAN layer, LDS double-buffered B ---------------------
// L1: 256 thr, NT=64, pos-gather A, out h1 fp16 via stage1 + uint4 copy.
// L2: 320 thr (5 waves x 32 rows = 160 rows = 8 pts), NT=128 (all cols,
//     features once), LDS union slab+Bbuf -> C-stage, fused maxpool -> x1.
// L3: 256 thr, NT=64, XCD-swizzled, max/sum butterfly -> pmax/psum.
template <int L>
__global__ __launch_bounds__((L == 2) ? 320 : 256, (L == 2) ? 4 : 3)
void kan_kernel(
    const void* __restrict__ in_, const int* __restrict__ nbr,
    const void* __restrict__ pos, const u16* __restrict__ ct,
    const void* __restrict__ bias, void* __restrict__ out_,
    float* __restrict__ pmax, float* __restrict__ psum,
    const int* __restrict__ dfl) {
  constexpr int W    = (L == 1) ? 3  : (L == 2) ? 16  : 32;
  constexpr int S    = (L == 1) ? 3  : (L == 2) ? 8   : 16;
  constexpr int DIN  = (L == 1) ? 6  : (L == 2) ? 64  : 128;
  constexpr int NTH  = (L == 2) ? 320 : 256;
  constexpr int NWV  = NTH / 64;
  constexpr int NT   = (L == 2) ? 128 : 64;
  constexpr int NW   = (DIN - W) / S + 1;
  constexpr int NA   = NW * W;                      // angles
  constexpr int NPAIR = NA * 5;
  constexpr int S1P  = NA * 4;                      // section-1 pairs (g=1..4)
  constexpr int KROW  = (L == 1) ? 64 : NPAIR * 2;  // ct row stride (padded L1)
  constexpr int NCH   = KROW / 32;
  constexpr int NB    = NT / 16;
  constexpr int RW    = (L == 1) ? 64 : 32;         // rows per wave
  constexpr int MB    = RW / 16;
  constexpr int PSTH  = DIN + 4;                    // slab stride (halves)
  constexpr int LGW   = (W == 16) ? 4 : 5;          // log2(W) for L2/L3
  constexpr int PRT   = NT * 8 + 16;                // Bbuf part stride (halves)
  constexpr int BBS   = 4 * PRT;                    // Bbuf halves per buffer
  constexpr int NPIECE = NT * 4;                    // 16B pieces per chunk
  constexpr int NLD   = (NPIECE + NTH - 1) / NTH;
  constexpr int ROWS  = NWV * RW;                   // rows per block

  __shared__ float hamS[(L == 1) ? 1 : W];
  __shared__ float wT1[(L == 1) ? 32 : 1];          // L1 tables (padded K=64)
  __shared__ int   hT1[(L == 1) ? 32 : 1];
  __shared__ u16   uni[(L == 2) ? 160 * 136 : 2];   // L2: slab+Bbuf / C-stage
  __shared__ u16   slabA[(L == 3) ? 4 * 32 * 132 : 2];
  __shared__ u16   BbufA[(L == 2) ? 2 : 2 * BBS];
  __shared__ u16   stage1[(L == 1) ? 4 * 64 * 64 : 2];

  u16* slab = (L == 2) ? uni : slabA;
  u16* Bbuf = (L == 2) ? (uni + 160 * 68) : BbufA;  // 21,760B offset, 16B-aligned

  const bool f32 = (*dfl != 0);
  const u16* inH = (const u16*)in_;
  const int t = threadIdx.x;
  if constexpr (L == 1) {
    if (t < 32) {
      float wv_ = 0.f; int hx = 0;
      if (t < NPAIR) {                              // angle-major mapping
        int aa, gg;
        if (t < S1P) { aa = t >> 2;   gg = t & 3; }
        else         { aa = t - S1P;  gg = 4;     }
        int i = aa % W;
        float hm = 0.54f - 0.46f * cospif(2.0f * (float)i / (float)(W - 1));
        wv_ = hm * (float)(gg + 1);
        hx = aa;                                    // L1 uses aa directly
      }
      wT1[t] = wv_; hT1[t] = hx;
    }
  } else {
    if (t < W) hamS[t] = 0.54f - 0.46f * cospif(2.0f * (float)t / (float)(W - 1));
  }

  // ---- block index: L3 uses XCD-aware swizzle (id%8-equal share 2 slices) --
  int tile, ncol0;
  if constexpr (L == 3) {
    const int id = blockIdx.x;                      // 1024 linear
    tile = (id >> 3) & 63;
    ncol0 = ((((id & 7) << 1) | (id >> 9))) * NT;
  } else {
    tile = blockIdx.x;
    ncol0 = 0;
  }
  const int lane = t & 63, wv = t >> 6;
  const int m16 = lane & 15, kb = lane >> 4;
  const int rowbase = tile * ROWS + wv * RW;
  u16* myslab = slab + ((L == 1) ? 0 : wv * RW * PSTH);

  // ---- stage wave-private fp16 slab (L>=2): uint2 = 4 halves ----
  if constexpr (L >= 2) {
    constexpr int F4R = DIN / 4;
    constexpr int TOT = RW * F4R;
    for (int i = lane; i < TOT; i += 64) {
      const int r = i / F4R, c4 = i % F4R;
      *(uint2*)(myslab + r * PSTH + c4 * 4) =
          *(const uint2*)(inH + (size_t)(rowbase + r) * DIN + c4 * 4);
    }
  }

  // ---- prologue: stage B chunk 0 ----
#pragma unroll
  for (int ii = 0; ii < NLD; ++ii) {
    const int i = t + ii * NTH;
    if (i < NPIECE) {
      const uint4 v = *(const uint4*)(ct +
          (size_t)(ncol0 + (i >> 2)) * KROW + (i & 3) * 8);
      *(uint4*)(Bbuf + (i & 3) * PRT + (i >> 2) * 8) = v;
    }
  }
  __syncthreads();  // covers hamS/tables + Bbuf[0]

  f32x4 acc[MB][NB];
#pragma unroll
  for (int mb = 0; mb < MB; ++mb)
#pragma unroll
    for (int nb = 0; nb < NB; ++nb) {
      acc[mb][nb][0] = 0.f; acc[mb][nb][1] = 0.f;
      acc[mb][nb][2] = 0.f; acc[mb][nb][3] = 0.f;
    }

  for (int c = 0; c < NCH; ++c) {
    // ---- issue next chunk's B load (per BLOCK, coalesced) ----
    uint4 bn[NLD];
    const bool havenext = (c + 1 < NCH);
    if (havenext) {
#pragma unroll
      for (int ii = 0; ii < NLD; ++ii) {
        const int i = t + ii * NTH;
        if (i < NPIECE)
          bn[ii] = *(const uint4*)(ct +
              (size_t)(ncol0 + (i >> 2)) * KROW + (c + 1) * 32 + (i & 3) * 8);
      }
    }
    // ---- A fragments for chunk c ----
    const int pg0 = c * 16 + kb * 4;
    half8 af[MB];
    if constexpr (L == 1) {
      float wm[4]; int hx[4]; bool val[4];
#pragma unroll
      for (int u = 0; u < 4; ++u) {
        const int pg = pg0 + u;
        wm[u] = wT1[pg]; hx[u] = hT1[pg]; val[u] = (pg < NPAIR);
      }
#pragma unroll
      for (int mb = 0; mb < MB; ++mb) {
        const int row = rowbase + mb * 16 + m16;
        const int pt = row / 20;
        const int cloud = pt >> 10, ci = pt & 1023;
        const int cb = cloud << 10;
        const int jl = nbr[row];
#pragma unroll
        for (int u = 0; u < 4; ++u) {
          float cs = 0.f, sn = 0.f;
          if (val[u]) {
            const int aa = hx[u];
            float v;
            if (aa < 3) {
              v = ldf(pos, (size_t)(cb + ci) * 3 + aa, f32);
            } else {
              const int cc2 = aa - 3;
              v = ldf(pos, (size_t)(cb + jl) * 3 + cc2, f32) -
                  ldf(pos, (size_t)(cb + ci) * 3 + cc2, f32);
            }
            const float ang = v * wm[u];
            cs = __cosf(ang); sn = __sinf(ang);
          }
          af[mb][2 * u]     = (_Float16)cs;
          af[mb][2 * u + 1] = (_Float16)sn;
        }
      }
    } else if (pg0 < S1P) {
      // section 1: one angle, g=1..4 -> Chebyshev recurrence
      const int aa = pg0 >> 2;
      const int i = aa & (W - 1), w = aa >> LGW;
      const int hidx = S * w + i;
      const float hm = hamS[i];
#pragma unroll
      for (int mb = 0; mb < MB; ++mb) {
        const u16* rp = myslab + (mb * 16 + m16) * PSTH;
        const float th = h2f(rp[hidx]) * hm;
        const float c1 = __cosf(th), s1 = __sinf(th);
        const float tc = 2.0f * c1;
        const float c2 = tc * c1 - 1.0f, s2 = tc * s1;
        const float c3 = tc * c2 - c1,   s3 = tc * s2 - s1;
        const float c4 = tc * c3 - c2,   s4 = tc * s3 - s2;
        af[mb][0] = (_Float16)c1; af[mb][1] = (_Float16)s1;
        af[mb][2] = (_Float16)c2; af[mb][3] = (_Float16)s2;
        af[mb][4] = (_Float16)c3; af[mb][5] = (_Float16)s3;
        af[mb][6] = (_Float16)c4; af[mb][7] = (_Float16)s4;
      }
    } else {
      // section 2: g=5 tail, 4 distinct angles, direct cos/sin
      const int q0 = pg0 - S1P;
      float wm[4]; int hx[4];
#pragma unroll
      for (int u = 0; u < 4; ++u) {
        const int aa = q0 + u;
        const int i = aa & (W - 1), w = aa >> LGW;
        hx[u] = S * w + i;
        wm[u] = hamS[i] * 5.0f;
      }
#pragma unroll
      for (int mb = 0; mb < MB; ++mb) {
        const u16* rp = myslab + (mb * 16 + m16) * PSTH;
#pragma unroll
        for (int u = 0; u < 4; ++u) {
          const float ang = h2f(rp[hx[u]]) * wm[u];
          af[mb][2 * u]     = (_Float16)__cosf(ang);
          af[mb][2 * u + 1] = (_Float16)__sinf(ang);
        }
      }
    }
    // ---- B fragments from LDS + MFMA ----
    const u16* bb = Bbuf + (c & 1) * BBS + kb * PRT;
#pragma unroll
    for (int nb = 0; nb < NB; ++nb) {
      const half8 bv = *(const half8*)(bb + (nb * 16 + m16) * 8);
#pragma unroll
      for (int mb = 0; mb < MB; ++mb)
        acc[mb][nb] = __builtin_amdgcn_mfma_f32_16x16x32_f16(
            af[mb], bv, acc[mb][nb], 0, 0, 0);
    }
    // ---- commit next chunk's B to LDS, barrier ----
    if (havenext) {
#pragma unroll
      for (int ii = 0; ii < NLD; ++ii) {
        const int i = t + ii * NTH;
        if (i < NPIECE)
          *(uint4*)(Bbuf + ((c + 1) & 1) * BBS + (i & 3) * PRT + (i >> 2) * 8)
              = bn[ii];
      }
      __syncthreads();
    }
  }

  // ---- fused epilogues (C layout: row=kb*4+r, col=m16 within 16x16) ----
  if constexpr (L == 1) {
    // stage wave C-tile (64 rows x 64 cols fp16) then contiguous copy out
    u16* st = &stage1[wv * 4096];
#pragma unroll
    for (int mb = 0; mb < MB; ++mb)
#pragma unroll
      for (int nb = 0; nb < NB; ++nb) {
        const float bsv = ldf(bias, nb * 16 + m16, f32);
#pragma unroll
        for (int r = 0; r < 4; ++r)
          st[(mb * 16 + kb * 4 + r) * 64 + nb * 16 + m16] =
              f2h(acc[mb][nb][r] + bsv);
      }
    u16* gp = (u16*)out_ + (size_t)rowbase * 64;
    for (int i = lane; i < 512; i += 64)        // 512 x 16B = 8KB
      *(uint4*)(gp + i * 8) = *(const uint4*)&st[i * 8];
  } else if constexpr (L == 2) {
    // block-wide C-stage into uni (stride 136), then pooled maxpool -> x1
    __syncthreads();  // all waves done reading slab/Bbuf
#pragma unroll
    for (int mb = 0; mb < MB; ++mb)
#pragma unroll
      for (int nb = 0; nb < NB; ++nb) {
        const int col = nb * 16 + m16;
        const float bsv = ldf(bias, col, f32);
#pragma unroll
        for (int r = 0; r < 4; ++r)
          uni[(wv * 32 + mb * 16 + kb * 4 + r) * 136 + col] =
              f2h(acc[mb][nb][r] + bsv);
      }
    __syncthreads();
    for (int i = t; i < 1024; i += NTH) {       // 8 points x 128 cols
      const int p = i >> 7, j = i & 127;
      float m = -3.0e38f;
#pragma unroll
      for (int k = 0; k < 20; ++k)
        m = fmaxf(m, h2f(uni[(p * 20 + k) * 136 + j]));
      ((u16*)out_)[(size_t)(tile * 8 + p) * 128 + j] = f2h(m);
    }
  } else {
    // in-register max/sum over 32 rows + kb butterfly -> pmax/psum partials
    const int chunk = rowbase >> 5;
#pragma unroll
    for (int nb = 0; nb < NB; ++nb) {
      const int col = ncol0 + nb * 16 + m16;
      const float bsv = ldf(bias, col, f32);
      float m = -3.0e38f, s = 0.f;
#pragma unroll
      for (int mb = 0; mb < MB; ++mb)
#pragma unroll
        for (int r = 0; r < 4; ++r) {
          const float v = acc[mb][nb][r] + bsv;
          m = fmaxf(m, v); s += v;
        }
#pragma unroll
      for (int off = 16; off <= 32; off <<= 1) {
        m = fmaxf(m, __shfl_xor(m, off, 64));
        s += __shfl_xor(s, off, 64);
      }
      if (kb == 0) {
        pmax[(size_t)chunk * 1024 + col] = m;
        psum[(size_t)chunk * 1024 + col] = s;
      }
    }
  }
}

// ---------------- layer 4 partials (seg reduce fused in) --------------------
// c4t GLOBAL layout (angle-major): window w section-1 (g1..4 quads) at
// o*38400 + w*2048 ; g5 tail at o*38400 + 30720 + w*512.
__global__ __launch_bounds__(256) void l4_kernel(const float* __restrict__ pmax,
                                                 const float* __restrict__ psum,
                                                 const float* __restrict__ c4t,
                                                 float* __restrict__ part) {
  __shared__ float F[2560];
  const int t = threadIdx.x;
  const int w = blockIdx.x, b = blockIdx.y;
  // fused segment combine (same reduce order as former seg2)
  const int ch = w * 128 + t;
  float xv;
  if (ch < 1024) {
    float m = -3.0e38f;
    for (int rc = 0; rc < 32; ++rc)
      m = fmaxf(m, pmax[(size_t)(b * 32 + rc) * 1024 + ch]);
    xv = m;
  } else {
    const int cc = ch - 1024;
    float s = 0.f;
    for (int rc = 0; rc < 32; ++rc)
      s += psum[(size_t)(b * 32 + rc) * 1024 + cc];
    xv = s * (1.0f / 1024.0f);
  }
  const float hm = 0.54f - 0.46f * cospif(2.0f * (float)t / 255.0f);
  const float aa = xv * hm;
  const float c1 = __cosf(aa), s1 = __sinf(aa);
  const float tc = 2.0f * c1;
  const float c2 = tc * c1 - 1.0f, s2 = tc * s1;
  const float c3 = tc * c2 - c1,   s3 = tc * s2 - s1;
  const float c4 = tc * c3 - c2,   s4 = tc * s3 - s2;
  const float a5 = aa * 5.0f;
  F[t * 8]     = c1; F[t * 8 + 1] = s1;
  F[t * 8 + 2] = c2; F[t * 8 + 3] = s2;
  F[t * 8 + 4] = c3; F[t * 8 + 5] = s3;
  F[t * 8 + 6] = c4; F[t * 8 + 7] = s4;
  F[2048 + t * 2]     = __cosf(a5);
  F[2048 + t * 2 + 1] = __sinf(a5);
  __syncthreads();
  if (t < 240) {
    const int o = t % 40, s = t / 40;
    const int f0 = s * 432;
    const int f1 = (f0 + 432 < 2560) ? (f0 + 432) : 2560;
    const float* cp1 = c4t + (size_t)o * 38400 + w * 2048;          // sec 1
    const float* cp2 = c4t + (size_t)o * 38400 + 30720 + w * 512;   // g5 tail
    float acc = 0.f;
    for (int f = f0; f < f1; f += 4) {   // 2048 boundary is float4-aligned
      const float* cpf = (f < 2048) ? (cp1 + f) : (cp2 + (f - 2048));
      const float4 cv = *(const float4*)cpf;
      const float4 fa = *(const float4*)&F[f];
      acc += fa.x * cv.x + fa.y * cv.y + fa.z * cv.z + fa.w * cv.w;
    }
    part[((b * 15 + w) * 6 + s) * 40 + o] = acc;
  }
}

__global__ void outred_kernel(const float* __restrict__ part,
                              const void* __restrict__ b4,
                              void* __restrict__ outp,
                              const int* __restrict__ dfl) {
  int t = threadIdx.x;
  if (t >= 320) return;
  const bool f32 = (*dfl != 0);
  int b = t / 40, o = t % 40;
  float s = ldf(b4, o, f32);
  for (int w = 0; w < 15; ++w)
#pragma unroll
    for (int sl = 0; sl < 6; ++sl)
      s += part[((b * 15 + w) * 6 + sl) * 40 + o];
  if (f32) ((float*)outp)[t] = s;
  else     ((u16*)outp)[t] = f2bfr(s);
}

// ---------------------------------------------------------------------------
extern "C" void kernel_launch(void* const* d_in, const int* in_sizes, int n_in,
                              void* d_out, int out_size, void* d_ws,
                              size_t ws_size, hipStream_t stream) {
  (void)in_sizes; (void)n_in; (void)out_size; (void)ws_size;
  const void* pos = d_in[0];
  // d_in[1] = batch (int32) -- clouds are sorted equal-size, used implicitly
  const void* c1 = d_in[2];
  const void* b1 = d_in[3];
  const void* c2 = d_in[4];
  const void* b2 = d_in[5];
  const void* c3 = d_in[6];
  const void* b3 = d_in[7];
  const void* c4 = d_in[8];
  const void* b4 = d_in[9];

  char* ws = (char*)d_ws;
  int* nbr   = (int*)(ws + NBR_OFF);
  int* flag  = (int*)(ws + FLAG_OFF);
  float* l4p = (float*)(ws + L4P_OFF);
  u16* c1t   = (u16*)(ws + C1T_OFF);
  u16* c2t   = (u16*)(ws + C2T_OFF);
  u16* c3t   = (u16*)(ws + C3T_OFF);
  float* c4t = (float*)(ws + C4T_OFF);
  float* pmax = (float*)(ws + PMAX_OFF);
  float* psum = (float*)(ws + PSUM_OFF);
  u16* x1    = (u16*)(ws + X1_OFF);
  u16* h1    = (u16*)(ws + H1_OFF);

  detect_kernel<<<1, 64, 0, stream>>>(pos, flag);

  tkan_all_kernel<<<15536, 256, 0, stream>>>(c1, c1t, c2, c2t, c3, c3t,
                                             c4, c4t, flag);

  knn_kernel<<<dim3(256, 8), 256, 0, stream>>>(pos, nbr, flag);

  // L1: 640 blocks x 256 rows, NT=DOUT=64
  kan_kernel<1><<<640, 256, 0, stream>>>(nullptr, nbr, pos, c1t, b1, h1,
                                         nullptr, nullptr, flag);
  // L2 fused maxpool: 1024 blocks x 160 rows (8 points), all 128 cols
  kan_kernel<2><<<1024, 320, 0, stream>>>(h1, nullptr, nullptr, c2t,
                                          b2, x1, nullptr, nullptr, flag);
  // L3 fused segment partials: 1024 linear blocks, XCD-swizzled inside
  kan_kernel<3><<<1024, 256, 0, stream>>>(x1, nullptr, nullptr, c3t,
                                          b3, nullptr, pmax, psum, flag);

  l4_kernel<<<dim3(15, 8), 256, 0, stream>>>(pmax, psum, c4t, l4p);
  outred_kernel<<<1, 320, 0, stream>>>(l4p, b4, d_out, flag);
}

// Round 20
// 308.908 us; speedup vs baseline: 1.1765x; 1.1765x over previous
//
#include <hip/hip_runtime.h>

// ---------------------------------------------------------------------------
// STFT-Fourier-KAN DGCNN on MI355X.
// R19 post-mortem: single-pass kan<2> (RW=32,NT=128) REGRESSED 77->142us.
// VALU dropped 51->17.5% (recompute elimination worked) but the kernel went
// latency-bound: per-wave work per chunk fell to 2 trans-groups (was 5+20
// redundant) -- the "redundant" feature compute was the latency hider.
// Conflicts doubled (9.2M) with the 8KB B-tile. No recompute-free shape
// fits both the fused maxpool (rows % 20 == 0) and the VGPR budget.
// R20: revert kan<2> to the measured-77us R18 shape (256thr, RW=80, NT=64,
// y=2, 52.2KB LDS, 3 blocks/CU); keep R19's seg2-into-l4 fusion.
// ---------------------------------------------------------------------------

typedef unsigned short u16;
typedef unsigned int   u32;
typedef unsigned long long u64;
typedef __attribute__((ext_vector_type(8))) _Float16 half8;
typedef __attribute__((ext_vector_type(4))) float f32x4;

__device__ __forceinline__ float bf2f(u16 u) {
  u32 v = ((u32)u) << 16;
  return __uint_as_float(v);
}
__device__ __forceinline__ u16 f2bfr(float f) {  // bf16 round-to-nearest-even
  u32 x = __float_as_uint(f);
  u32 r = x + 0x7FFFu + ((x >> 16) & 1u);
  return (u16)(r >> 16);
}
__device__ __forceinline__ u16 f2h(float f) {    // fp16 RTN bits
  _Float16 h = (_Float16)f;
  u16 r;
  __builtin_memcpy(&r, &h, 2);
  return r;
}
__device__ __forceinline__ float h2f(u16 u) {
  _Float16 h;
  __builtin_memcpy(&h, &u, 2);
  return (float)h;
}
// dtype-dispatched external load (flag wave-uniform -> scalar branch)
__device__ __forceinline__ float ldf(const void* p, size_t i, bool f32) {
  return f32 ? ((const float*)p)[i] : bf2f(((const u16*)p)[i]);
}
__device__ __forceinline__ u64 minu64(u64 a, u64 b) { return a < b ? a : b; }

// ---------------- workspace layout (bytes) ----------------
#define NBR_OFF   ((size_t)0)                       // int32 [163840]       655,360
#define FLAG_OFF  ((size_t)917504)                  // int32 [1]
#define L4P_OFF   (((size_t)(1u << 20)) + 131072)   // f32 [8][15][240]     115,200
#define C1T_OFF   (((size_t)(1u << 20)) + 524288)   // fp16 [64][64]          8,192
#define C2T_OFF   (((size_t)(1u << 20)) + 589824)   // fp16 [128][1120]     286,720
#define C3T_OFF   ((size_t)(2u << 20))              // fp16 [1024][2240]  4,587,520
#define C4T_OFF   ((size_t)(7u << 20))              // f32  [40][38400]   6,144,000
#define PMAX_OFF  ((size_t)(13u << 20))             // f32 [256][1024]    1,048,576
#define PSUM_OFF  ((size_t)(14u << 20))             // f32 [256][1024]    1,048,576
#define X1_OFF    ((size_t)(15u << 20))             // fp16 [8192][128]   2,097,152
#define H1_OFF    ((size_t)(18u << 20))             // fp16 [163840][64] 20,971,520
// peak ~39 MB

// ---------------- dtype detector -------------------------------------------
__global__ void detect_kernel(const void* __restrict__ pos,
                              int* __restrict__ flag) {
  int t = threadIdx.x;  // 64 threads
  float a = fabsf(((const float*)pos)[t]);
  bool ok = (a > 1.0e-3f && a < 100.0f);
  unsigned long long m = __ballot(ok);
  if (t == 0) *flag = (__popcll(m) >= 32) ? 1 : 0;  // 1 = fp32 externals
}

// ---------------- merged coeff transpose: all four tensors ------------------
// Angle-major global order: p < 4*NA: aa=p>>2, g=(p&3)+1 ;
// p in [4*NA,5*NA): aa=p-4*NA, g=5. f = 2*p + part. Pad f>=Kt with zeros.
// Block ranges: c1 [0,16) c2 [16,576) c3 [576,9536) c4 [9536,15536).
__global__ void tkan_all_kernel(const void* __restrict__ s1, void* __restrict__ d1,
                                const void* __restrict__ s2, void* __restrict__ d2,
                                const void* __restrict__ s3, void* __restrict__ d3,
                                const void* __restrict__ s4, void* __restrict__ d4,
                                const int* __restrict__ dfl) {
  const int blk = blockIdx.x;
  const void* src; void* dst;
  int dout, nw, W, total, KPAD, outf32, base;
  if (blk < 16)        { src = s1; dst = d1; dout = 64;   nw = 2;  W = 3;
                         total = 64 * 64;     KPAD = 64;    outf32 = 0; base = 0; }
  else if (blk < 576)  { src = s2; dst = d2; dout = 128;  nw = 7;  W = 16;
                         total = 128 * 1120;  KPAD = 1120;  outf32 = 0; base = 16; }
  else if (blk < 9536) { src = s3; dst = d3; dout = 1024; nw = 7;  W = 32;
                         total = 1024 * 2240; KPAD = 2240;  outf32 = 0; base = 576; }
  else                 { src = s4; dst = d4; dout = 40;   nw = 15; W = 256;
                         total = 40 * 38400;  KPAD = 38400; outf32 = 1; base = 9536; }
  int id = (blk - base) * 256 + threadIdx.x;
  if (id >= total) return;
  const bool f32 = (*dfl != 0);
  int o = id / KPAD, f = id % KPAD;
  int NA = nw * W;
  int Kt = NA * 10;
  float v = 0.f;
  if (f < Kt) {
    int part = f & 1, p = f >> 1;
    int aa, gg;
    if (p < 4 * NA) { aa = p >> 2;      gg = p & 3; }
    else            { aa = p - 4 * NA;  gg = 4;     }
    int i = aa % W, w = aa / W;
    int OS = NA * 5;
    size_t sidx = (size_t)part * (dout * OS) + (size_t)o * OS + w * (W * 5) + i * 5 + gg;
    v = ldf(src, sidx, f32);
  }
  if (outf32) ((float*)dst)[id] = v;
  else        ((u16*)dst)[id] = f2h(v);
}

// ---------------- brute-force kNN: one wave per query -----------------------
__global__ __launch_bounds__(256) void knn_kernel(const void* __restrict__ pos,
                                                  int* __restrict__ nbr,
                                                  const int* __restrict__ dfl) {
  __shared__ float px[1024], py[1024], pz[1024];
  const bool f32 = (*dfl != 0);
  const int t = threadIdx.x;
  const int b = blockIdx.y;
  const int base = b << 10;
  for (int j = t; j < 1024; j += 256) {
    size_t pidx = (size_t)(base + j) * 3;
    px[j] = ldf(pos, pidx, f32);
    py[j] = ldf(pos, pidx + 1, f32);
    pz[j] = ldf(pos, pidx + 2, f32);
  }
  __syncthreads();
  const int wv = t >> 6, lane = t & 63;
  const int q = blockIdx.x * 4 + wv;
  const float qx = px[q], qy = py[q], qz = pz[q];
  u64 key[16];
#pragma unroll
  for (int s = 0; s < 16; ++s) {
    const int j = s * 64 + lane;
    float dx = qx - px[j], dy = qy - py[j], dz = qz - pz[j];
    float d = __fadd_rn(__fadd_rn(__fmul_rn(dx, dx), __fmul_rn(dy, dy)),
                        __fmul_rn(dz, dz));
    key[s] = (j == q) ? ~0ull
                      : ((((u64)__float_as_uint(d)) << 32) | (u32)j);
  }
  const int obase = (base + q) * 20;
  for (int k = 0; k < 20; ++k) {
    u64 m = key[0];
#pragma unroll
    for (int s = 1; s < 16; ++s) m = minu64(m, key[s]);
#pragma unroll
    for (int off = 32; off >= 1; off >>= 1) {
      u32 lo = (u32)m, hi = (u32)(m >> 32);
      lo = __shfl_xor(lo, off, 64);
      hi = __shfl_xor(hi, off, 64);
      m = minu64(m, (((u64)hi) << 32) | lo);
    }
    if (lane == 0) nbr[obase + k] = (int)(u32)m;
#pragma unroll
    for (int s = 0; s < 16; ++s)
      if (key[s] == m) key[s] = ~0ull;  // idx embedded -> unique, safe
  }
}

// ---------------- MFMA KAN layer, LDS double-buffered B ---------------------
// Per chunk: 256 threads each load ONE 16B piece of next chunk's B (4KB per
// block, shared by all waves), compute current chunk (slab LDS + trans),
// MFMA from Bbuf ds_read_b128, then ds_write+barrier.
// PSTH=DIN+4 halves: lane stride (2*m16)%32 -> 16 distinct banks.
template <int L>
__global__ __launch_bounds__(256, 3) void kan_kernel(
    const void* __restrict__ in_, const int* __restrict__ nbr,
    const void* __restrict__ pos, const u16* __restrict__ ct,
    const void* __restrict__ bias, void* __restrict__ out_,
    float* __restrict__ pmax, float* __restrict__ psum,
    const int* __restrict__ dfl) {
  constexpr int W    = (L == 1) ? 3  : (L == 2) ? 16  : 32;
  constexpr int S    = (L == 1) ? 3  : (L == 2) ? 8   : 16;
  constexpr int DIN  = (L == 1) ? 6  : (L == 2) ? 64  : 128;
  constexpr int NT   = 64;                          // all layers: 64-col tiles
  constexpr int NW   = (DIN - W) / S + 1;
  constexpr int NA   = NW * W;                      // angles
  constexpr int NPAIR = NA * 5;
  constexpr int S1P  = NA * 4;                      // section-1 pairs (g=1..4)
  constexpr int KROW  = (L == 1) ? 64 : NPAIR * 2;  // ct row stride (padded L1)
  constexpr int NCH   = KROW / 32;
  constexpr int NB    = NT / 16;                    // 4
  constexpr int RW    = (L == 1) ? 64 : (L == 2) ? 80 : 32;  // rows per wave
  constexpr int MB    = RW / 16;
  constexpr int PSTH  = DIN + 4;                    // slab stride (halves)
  constexpr int LGW   = (W == 16) ? 4 : 5;          // log2(W) for L2/L3
  constexpr int BBS   = 4 * 520;                    // Bbuf halves per buffer

  __shared__ float hamS[(L == 1) ? 1 : W];
  __shared__ float wT1[(L == 1) ? 32 : 1];          // L1 tables (padded K=64)
  __shared__ int   hT1[(L == 1) ? 32 : 1];
  __shared__ u16   slab[(L == 1) ? 2 : 4 * RW * PSTH];
  __shared__ u16   stage1[(L == 1) ? 4 * 64 * 64 : 2];
  __shared__ u16   Bbuf[2 * BBS];                   // [buf][part(4)][520]

  const bool f32 = (*dfl != 0);
  const u16* inH = (const u16*)in_;
  const int t = threadIdx.x;
  if constexpr (L == 1) {
    if (t < 32) {
      float wv_ = 0.f; int hx = 0;
      if (t < NPAIR) {                              // angle-major mapping
        int aa, gg;
        if (t < S1P) { aa = t >> 2;   gg = t & 3; }
        else         { aa = t - S1P;  gg = 4;     }
        int i = aa % W;
        float hm = 0.54f - 0.46f * cospif(2.0f * (float)i / (float)(W - 1));
        wv_ = hm * (float)(gg + 1);
        hx = aa;                                    // L1 uses aa directly
      }
      wT1[t] = wv_; hT1[t] = hx;
    }
  } else {
    if (t < W) hamS[t] = 0.54f - 0.46f * cospif(2.0f * (float)t / (float)(W - 1));
  }

  // ---- block index: L3 uses XCD-aware swizzle (id%8-equal share 2 slices) --
  int tile, ncol0;
  if constexpr (L == 3) {
    const int id = blockIdx.x;                      // 1024 linear
    tile = (id >> 3) & 63;
    ncol0 = ((((id & 7) << 1) | (id >> 9))) * NT;
  } else {
    tile = blockIdx.x;
    ncol0 = blockIdx.y * NT;
  }
  const int lane = t & 63, wv = t >> 6;
  const int m16 = lane & 15, kb = lane >> 4;
  const int rowbase = tile * (4 * RW) + wv * RW;
  u16* myslab = &slab[(L == 1) ? 0 : wv * RW * PSTH];

  // B staging indices: thread t covers col=t>>2, part=t&3 (16B each)
  const int scol = t >> 2, spart = t & 3;
  const u16* srcB = ct + (size_t)(ncol0 + scol) * KROW + spart * 8;

  // ---- stage wave-private fp16 slab (L>=2): uint2 = 4 halves ----
  if constexpr (L >= 2) {
    constexpr int F4R = DIN / 4;
    constexpr int TOT = RW * F4R;
    for (int i = lane; i < TOT; i += 64) {
      const int r = i / F4R, c4 = i % F4R;
      *(uint2*)(myslab + r * PSTH + c4 * 4) =
          *(const uint2*)(inH + (size_t)(rowbase + r) * DIN + c4 * 4);
    }
  }

  // ---- prologue: stage B chunk 0 ----
  {
    const uint4 v = *(const uint4*)srcB;
    *(uint4*)(Bbuf + spart * 520 + scol * 8) = v;
  }
  __syncthreads();  // covers hamS/tables + Bbuf[0]

  f32x4 acc[MB][NB];
#pragma unroll
  for (int mb = 0; mb < MB; ++mb)
#pragma unroll
    for (int nb = 0; nb < NB; ++nb) {
      acc[mb][nb][0] = 0.f; acc[mb][nb][1] = 0.f;
      acc[mb][nb][2] = 0.f; acc[mb][nb][3] = 0.f;
    }

  for (int c = 0; c < NCH; ++c) {
    // ---- issue next chunk's B load (one 16B per thread, per BLOCK) ----
    uint4 bnext;
    const bool havenext = (c + 1 < NCH);
    if (havenext)
      bnext = *(const uint4*)(srcB + (c + 1) * 32);
    // ---- A fragments for chunk c ----
    const int pg0 = c * 16 + kb * 4;
    half8 af[MB];
    if constexpr (L == 1) {
      float wm[4]; int hx[4]; bool val[4];
#pragma unroll
      for (int u = 0; u < 4; ++u) {
        const int pg = pg0 + u;
        wm[u] = wT1[pg]; hx[u] = hT1[pg]; val[u] = (pg < NPAIR);
      }
#pragma unroll
      for (int mb = 0; mb < MB; ++mb) {
        const int row = rowbase + mb * 16 + m16;
        const int pt = row / 20;
        const int cloud = pt >> 10, ci = pt & 1023;
        const int cb = cloud << 10;
        const int jl = nbr[row];
#pragma unroll
        for (int u = 0; u < 4; ++u) {
          float cs = 0.f, sn = 0.f;
          if (val[u]) {
            const int aa = hx[u];
            float v;
            if (aa < 3) {
              v = ldf(pos, (size_t)(cb + ci) * 3 + aa, f32);
            } else {
              const int cc2 = aa - 3;
              v = ldf(pos, (size_t)(cb + jl) * 3 + cc2, f32) -
                  ldf(pos, (size_t)(cb + ci) * 3 + cc2, f32);
            }
            const float ang = v * wm[u];
            cs = __cosf(ang); sn = __sinf(ang);
          }
          af[mb][2 * u]     = (_Float16)cs;
          af[mb][2 * u + 1] = (_Float16)sn;
        }
      }
    } else if (pg0 < S1P) {
      // section 1: one angle, g=1..4 -> Chebyshev recurrence
      const int aa = pg0 >> 2;
      const int i = aa & (W - 1), w = aa >> LGW;
      const int hidx = S * w + i;
      const float hm = hamS[i];
#pragma unroll
      for (int mb = 0; mb < MB; ++mb) {
        const u16* rp = myslab + (mb * 16 + m16) * PSTH;
        const float th = h2f(rp[hidx]) * hm;
        const float c1 = __cosf(th), s1 = __sinf(th);
        const float tc = 2.0f * c1;
        const float c2 = tc * c1 - 1.0f, s2 = tc * s1;
        const float c3 = tc * c2 - c1,   s3 = tc * s2 - s1;
        const float c4 = tc * c3 - c2,   s4 = tc * s3 - s2;
        af[mb][0] = (_Float16)c1; af[mb][1] = (_Float16)s1;
        af[mb][2] = (_Float16)c2; af[mb][3] = (_Float16)s2;
        af[mb][4] = (_Float16)c3; af[mb][5] = (_Float16)s3;
        af[mb][6] = (_Float16)c4; af[mb][7] = (_Float16)s4;
      }
    } else {
      // section 2: g=5 tail, 4 distinct angles, direct cos/sin
      const int q0 = pg0 - S1P;
      float wm[4]; int hx[4];
#pragma unroll
      for (int u = 0; u < 4; ++u) {
        const int aa = q0 + u;
        const int i = aa & (W - 1), w = aa >> LGW;
        hx[u] = S * w + i;
        wm[u] = hamS[i] * 5.0f;
      }
#pragma unroll
      for (int mb = 0; mb < MB; ++mb) {
        const u16* rp = myslab + (mb * 16 + m16) * PSTH;
#pragma unroll
        for (int u = 0; u < 4; ++u) {
          const float ang = h2f(rp[hx[u]]) * wm[u];
          af[mb][2 * u]     = (_Float16)__cosf(ang);
          af[mb][2 * u + 1] = (_Float16)__sinf(ang);
        }
      }
    }
    // ---- B fragments from LDS + MFMA ----
    const u16* bb = Bbuf + (c & 1) * BBS + kb * 520;
#pragma unroll
    for (int nb = 0; nb < NB; ++nb) {
      const half8 bv = *(const half8*)(bb + (nb * 16 + m16) * 8);
#pragma unroll
      for (int mb = 0; mb < MB; ++mb)
        acc[mb][nb] = __builtin_amdgcn_mfma_f32_16x16x32_f16(
            af[mb], bv, acc[mb][nb], 0, 0, 0);
    }
    // ---- commit next chunk's B to LDS, barrier ----
    if (havenext) {
      *(uint4*)(Bbuf + ((c + 1) & 1) * BBS + spart * 520 + scol * 8) = bnext;
      __syncthreads();
    }
  }

  // ---- fused epilogues (C layout: row=kb*4+r, col=m16 within 16x16) ----
  if constexpr (L == 1) {
    // stage wave C-tile (64 rows x 64 cols fp16) then contiguous copy out
    u16* st = &stage1[wv * 4096];
#pragma unroll
    for (int mb = 0; mb < MB; ++mb)
#pragma unroll
      for (int nb = 0; nb < NB; ++nb) {
        const float bsv = ldf(bias, nb * 16 + m16, f32);
#pragma unroll
        for (int r = 0; r < 4; ++r)
          st[(mb * 16 + kb * 4 + r) * 64 + nb * 16 + m16] =
              f2h(acc[mb][nb][r] + bsv);
      }
    u16* gp = (u16*)out_ + (size_t)rowbase * 64;
    for (int i = lane; i < 512; i += 64)        // 512 x 16B = 8KB
      *(uint4*)(gp + i * 8) = *(const uint4*)&st[i * 8];
  } else if constexpr (L == 2) {
    // C-tile -> dead slab (stride PSTH), maxpool over 20 rows, write x1 fp16
    u16* st = myslab;
#pragma unroll
    for (int mb = 0; mb < MB; ++mb)
#pragma unroll
      for (int nb = 0; nb < NB; ++nb) {
        const float bsv = ldf(bias, ncol0 + nb * 16 + m16, f32);
#pragma unroll
        for (int r = 0; r < 4; ++r)
          st[(mb * 16 + kb * 4 + r) * PSTH + nb * 16 + m16] =
              f2h(acc[mb][nb][r] + bsv);
      }
    const int pbase = tile * 16 + wv * 4;       // 4 points per wave
#pragma unroll
    for (int j = 0; j < 4; ++j) {
      float m = -3.0e38f;
#pragma unroll
      for (int k = 0; k < 20; ++k)
        m = fmaxf(m, h2f(st[(j * 20 + k) * PSTH + lane]));
      ((u16*)out_)[(size_t)(pbase + j) * 128 + ncol0 + lane] = f2h(m);
    }
  } else {
    // in-register max/sum over 32 rows + kb butterfly -> pmax/psum partials
    const int chunk = rowbase >> 5;
#pragma unroll
    for (int nb = 0; nb < NB; ++nb) {
      const int col = ncol0 + nb * 16 + m16;
      const float bsv = ldf(bias, col, f32);
      float m = -3.0e38f, s = 0.f;
#pragma unroll
      for (int mb = 0; mb < MB; ++mb)
#pragma unroll
        for (int r = 0; r < 4; ++r) {
          const float v = acc[mb][nb][r] + bsv;
          m = fmaxf(m, v); s += v;
        }
#pragma unroll
      for (int off = 16; off <= 32; off <<= 1) {
        m = fmaxf(m, __shfl_xor(m, off, 64));
        s += __shfl_xor(s, off, 64);
      }
      if (kb == 0) {
        pmax[(size_t)chunk * 1024 + col] = m;
        psum[(size_t)chunk * 1024 + col] = s;
      }
    }
  }
}

// ---------------- layer 4 partials (seg reduce fused in) --------------------
// c4t GLOBAL layout (angle-major): window w section-1 (g1..4 quads) at
// o*38400 + w*2048 ; g5 tail at o*38400 + 30720 + w*512.
__global__ __launch_bounds__(256) void l4_kernel(const float* __restrict__ pmax,
                                                 const float* __restrict__ psum,
                                                 const float* __restrict__ c4t,
                                                 float* __restrict__ part) {
  __shared__ float F[2560];
  const int t = threadIdx.x;
  const int w = blockIdx.x, b = blockIdx.y;
  // fused segment combine (same reduce order as former seg2)
  const int ch = w * 128 + t;
  float xv;
  if (ch < 1024) {
    float m = -3.0e38f;
    for (int rc = 0; rc < 32; ++rc)
      m = fmaxf(m, pmax[(size_t)(b * 32 + rc) * 1024 + ch]);
    xv = m;
  } else {
    const int cc = ch - 1024;
    float s = 0.f;
    for (int rc = 0; rc < 32; ++rc)
      s += psum[(size_t)(b * 32 + rc) * 1024 + cc];
    xv = s * (1.0f / 1024.0f);
  }
  const float hm = 0.54f - 0.46f * cospif(2.0f * (float)t / 255.0f);
  const float aa = xv * hm;
  const float c1 = __cosf(aa), s1 = __sinf(aa);
  const float tc = 2.0f * c1;
  const float c2 = tc * c1 - 1.0f, s2 = tc * s1;
  const float c3 = tc * c2 - c1,   s3 = tc * s2 - s1;
  const float c4 = tc * c3 - c2,   s4 = tc * s3 - s2;
  const float a5 = aa * 5.0f;
  F[t * 8]     = c1; F[t * 8 + 1] = s1;
  F[t * 8 + 2] = c2; F[t * 8 + 3] = s2;
  F[t * 8 + 4] = c3; F[t * 8 + 5] = s3;
  F[t * 8 + 6] = c4; F[t * 8 + 7] = s4;
  F[2048 + t * 2]     = __cosf(a5);
  F[2048 + t * 2 + 1] = __sinf(a5);
  __syncthreads();
  if (t < 240) {
    const int o = t % 40, s = t / 40;
    const int f0 = s * 432;
    const int f1 = (f0 + 432 < 2560) ? (f0 + 432) : 2560;
    const float* cp1 = c4t + (size_t)o * 38400 + w * 2048;          // sec 1
    const float* cp2 = c4t + (size_t)o * 38400 + 30720 + w * 512;   // g5 tail
    float acc = 0.f;
    for (int f = f0; f < f1; f += 4) {   // 2048 boundary is float4-aligned
      const float* cpf = (f < 2048) ? (cp1 + f) : (cp2 + (f - 2048));
      const float4 cv = *(const float4*)cpf;
      const float4 fa = *(const float4*)&F[f];
      acc += fa.x * cv.x + fa.y * cv.y + fa.z * cv.z + fa.w * cv.w;
    }
    part[((b * 15 + w) * 6 + s) * 40 + o] = acc;
  }
}

__global__ void outred_kernel(const float* __restrict__ part,
                              const void* __restrict__ b4,
                              void* __restrict__ outp,
                              const int* __restrict__ dfl) {
  int t = threadIdx.x;
  if (t >= 320) return;
  const bool f32 = (*dfl != 0);
  int b = t / 40, o = t % 40;
  float s = ldf(b4, o, f32);
  for (int w = 0; w < 15; ++w)
#pragma unroll
    for (int sl = 0; sl < 6; ++sl)
      s += part[((b * 15 + w) * 6 + sl) * 40 + o];
  if (f32) ((float*)outp)[t] = s;
  else     ((u16*)outp)[t] = f2bfr(s);
}

// ---------------------------------------------------------------------------
extern "C" void kernel_launch(void* const* d_in, const int* in_sizes, int n_in,
                              void* d_out, int out_size, void* d_ws,
                              size_t ws_size, hipStream_t stream) {
  (void)in_sizes; (void)n_in; (void)out_size; (void)ws_size;
  const void* pos = d_in[0];
  // d_in[1] = batch (int32) -- clouds are sorted equal-size, used implicitly
  const void* c1 = d_in[2];
  const void* b1 = d_in[3];
  const void* c2 = d_in[4];
  const void* b2 = d_in[5];
  const void* c3 = d_in[6];
  const void* b3 = d_in[7];
  const void* c4 = d_in[8];
  const void* b4 = d_in[9];

  char* ws = (char*)d_ws;
  int* nbr   = (int*)(ws + NBR_OFF);
  int* flag  = (int*)(ws + FLAG_OFF);
  float* l4p = (float*)(ws + L4P_OFF);
  u16* c1t   = (u16*)(ws + C1T_OFF);
  u16* c2t   = (u16*)(ws + C2T_OFF);
  u16* c3t   = (u16*)(ws + C3T_OFF);
  float* c4t = (float*)(ws + C4T_OFF);
  float* pmax = (float*)(ws + PMAX_OFF);
  float* psum = (float*)(ws + PSUM_OFF);
  u16* x1    = (u16*)(ws + X1_OFF);
  u16* h1    = (u16*)(ws + H1_OFF);

  detect_kernel<<<1, 64, 0, stream>>>(pos, flag);

  tkan_all_kernel<<<15536, 256, 0, stream>>>(c1, c1t, c2, c2t, c3, c3t,
                                             c4, c4t, flag);

  knn_kernel<<<dim3(256, 8), 256, 0, stream>>>(pos, nbr, flag);

  // L1: 640 blocks x 256 rows, NT=DOUT=64
  kan_kernel<1><<<640, 256, 0, stream>>>(nullptr, nbr, pos, c1t, b1, h1,
                                         nullptr, nullptr, flag);
  // L2 fused maxpool: 512 x-blocks x 320 rows (16 points), y=2 col-halves
  kan_kernel<2><<<dim3(512, 2), 256, 0, stream>>>(h1, nullptr, nullptr, c2t,
                                                  b2, x1, nullptr, nullptr, flag);
  // L3 fused segment partials: 1024 linear blocks, XCD-swizzled inside
  kan_kernel<3><<<1024, 256, 0, stream>>>(x1, nullptr, nullptr, c3t,
                                          b3, nullptr, pmax, psum, flag);

  l4_kernel<<<dim3(15, 8), 256, 0, stream>>>(pmax, psum, c4t, l4p);
  outred_kernel<<<1, 320, 0, stream>>>(l4p, b4, d_out, flag);
}